// Round 9
// baseline (155.129 us; speedup 1.0000x reference)
//
#include <hip/hip_runtime.h>
#include <hip/hip_bf16.h>
#include <stdint.h>

// STFT as GEMM:  C[b,t,n] = sum_k frames[b,t,k] * basis[k, col(n)]
//   frames[b,t,k] = reflect_pad(x[b])[t*512 + k]   (pad 512 both sides)
//   col(n) = n+1 for n<512 (re half), n+2 for n>=512 (im half)
// Output: d_out = [re (8*4097*512) | im (8*4097*512)] fp32.
//
// v8 = v7 + counted-vmcnt pipeline (T3/T4-lite), minimal safe form:
//   * bv (B frags) double-buffered in registers: bv(t+1) issued one full
//     half-iteration before use -> L2 latency off the MFMA critical path.
//   * A triple-buffered LDS (3x16KB): stage(t+2) issued during tile t.
//   * No __syncthreads drain: raw s_barrier preceded by s_waitcnt vmcnt(12).
//     Ledger: every half-iteration issues {8 bv + 4 GLL16}; at each barrier
//     only the 12 newest ops (next-bv + next-stage) may stay in flight, so
//     vmcnt(12) retires everything older (incl. the stage for the buffer
//     about to be read). Robust to compiler auto-waits (they only retire
//     more). Tail clamps kt to 15 (redundant stages, race-checked) to keep
//     the count uniform. Load groups pinned with sched_barrier(0).
//   Only asm: s_waitcnt vmcnt(12). No asm loads (v5 crash class avoided).

#define NX       2097152
#define NFRAMES  4097
#define NBATCH   8
#define KDIM     1024
#define BASIS_LD 1026
#define HALF_SZ  (NBATCH * NFRAMES * 512)

#define PADLEN   2163712   // 4224*512 + 1024, per batch
#define XP_BYTES ((size_t)NBATCH * PADLEN * 2)
#define BFRAG_OFF XP_BYTES
#define BFRAG_BYTES ((size_t)64 * 32 * 64 * 8 * 2)   // 2 MB
#define WS_NEEDED (BFRAG_OFF + BFRAG_BYTES)

#define MTILES 33  // ceil(4097/128)
#define NTILES 8   // 1024/128
#define GRID   (NBATCH * MTILES * NTILES)  // 2112 = 8 * 264

typedef __attribute__((ext_vector_type(8))) short bf16x8;
typedef __attribute__((ext_vector_type(4))) float f32x4;

#define GLL16(src, dst) __builtin_amdgcn_global_load_lds( \
    (const __attribute__((address_space(1))) unsigned int*)(src), \
    (__attribute__((address_space(3))) unsigned int*)(dst), 16, 0, 0)

static __device__ __forceinline__ unsigned short f2bf(float f) {
    union { float f; uint32_t u; } v; v.f = f;
    uint32_t r = (v.u + 0x7FFFu + ((v.u >> 16) & 1u)) >> 16;  // RNE
    return (unsigned short)r;
}

// ---------------------------------------------------------------------------
// Kernel 0: x fp32 -> reflect-padded bf16 xp (per-batch PADLEN elems).
// ---------------------------------------------------------------------------
__global__ void convert_pad(const float* __restrict__ x,
                            unsigned short* __restrict__ xp) {
    const int per = PADLEN >> 2;
    int gid = blockIdx.x * 256 + threadIdx.x;
    int b   = gid / per;
    int i4  = (gid - b * per) << 2;
    const float* xb = x + (size_t)b * NX;
    int j = i4 - 512;
    unsigned short s0, s1, s2, s3;
    if (j >= 0 && j + 3 < NX) {
        float4 f = *(const float4*)(xb + j);
        s0 = f2bf(f.x); s1 = f2bf(f.y); s2 = f2bf(f.z); s3 = f2bf(f.w);
    } else {
        unsigned short ss[4];
        #pragma unroll
        for (int e = 0; e < 4; ++e) {
            int i = i4 + e;
            float v = 0.0f;
            if (i < NX + 1024) {
                int jj = i - 512;
                if (jj < 0) jj = -jj;
                else if (jj >= NX) jj = 2 * (NX - 1) - jj;
                v = xb[jj];
            }
            ss[e] = f2bf(v);
        }
        s0 = ss[0]; s1 = ss[1]; s2 = ss[2]; s3 = ss[3];
    }
    union { unsigned short s[4]; uint2 u; } p;
    p.s[0] = s0; p.s[1] = s1; p.s[2] = s2; p.s[3] = s3;
    *(uint2*)(xp + (size_t)b * PADLEN + i4) = p.u;
}

// ---------------------------------------------------------------------------
// Kernel 1: basis -> Bfrag in MFMA-fragment order.
//   Bfrag elem offset = ((fn*32 + ks32)*64 + lane)*8 + j
//     holds bf16(basis[ks32*32 + (lane>>4)*8 + j][col(fn*16 + (lane&15))])
// One (fn,ks32) fragment = 64 lanes x 16B contiguous -> coalesced frag loads.
// ---------------------------------------------------------------------------
__global__ void basis_to_frag(const float* __restrict__ basis,
                              unsigned short* __restrict__ Bfrag) {
    int idx  = blockIdx.x * 256 + threadIdx.x;   // 0..131071
    int lane = idx & 63;
    int ks32 = (idx >> 6) & 31;
    int fn   = idx >> 11;                        // 0..63
    int n    = fn * 16 + (lane & 15);
    int kb   = ks32 * 32 + (lane >> 4) * 8;
    int col  = n + 1 + (n >= 512);
    #pragma unroll
    for (int j = 0; j < 8; ++j)
        Bfrag[(size_t)idx * 8 + j] = f2bf(basis[(size_t)(kb + j) * BASIS_LD + col]);
}

// ---------------------------------------------------------------------------
// Kernel 2: 128x128 bf16 MFMA GEMM, counted-vmcnt pipeline.
// 4 waves (2x2), 64x64 quadrant/wave, BK=64, 16 K-tiles processed in 8
// pair-iterations (static bvE/bvF register sets).
// ---------------------------------------------------------------------------
__global__ __launch_bounds__(256, 3) void stft_gemm7(
    const unsigned short* __restrict__ xp,
    const unsigned short* __restrict__ Bfrag,
    float* __restrict__ out)
{
    __shared__ unsigned short Al[3][128 * 64];   // 3 x 16 KB, A triple-buffer

    const int bid = blockIdx.x;
    const int wg  = (bid & 7) * (GRID / 8) + (bid >> 3);   // bijective XCD swizzle
    const int ntile = wg & 7;
    const int mtile = (wg >> 3) % MTILES;
    const int batch = wg / (MTILES * NTILES);

    const int tid  = threadIdx.x;
    const int lane = tid & 63;
    const int wr   = tid >> 7;         // wave row 0..1
    const int wc   = (tid >> 6) & 1;   // wave col 0..1
    const int t0   = mtile * 128;
    const int n0   = ntile * 128;

    const unsigned short* __restrict__ xpb = xp + (size_t)batch * PADLEN;
    const int l15 = lane & 15, l4 = lane >> 4;

    // this wave's B fragment base: fn0 = (n0 + wc*64)/16
    const unsigned short* __restrict__ bfr =
        Bfrag + (size_t)(ntile * 8 + wc * 4) * 16384 + lane * 8;

    f32x4 acc[4][4];
    #pragma unroll
    for (int m = 0; m < 4; ++m)
        #pragma unroll
        for (int n = 0; n < 4; ++n)
            acc[m][n] = (f32x4)0.0f;

    bf16x8 bvE[2][4], bvF[2][4];   // B frags, static double-buffer [s][n]

    // ---- A staging: 1024 x 16B chunks, linear LDS dest, swizzled source ----
    #define STAGE_A(KT, BUF) { \
        _Pragma("unroll") \
        for (int i = 0; i < 4; ++i) { \
            int q   = i * 256 + tid; \
            int row = q >> 3, d = q & 7; \
            const unsigned short* src = xpb \
                + (size_t)(t0 + row) * 512 + (KT) * 64 + ((d ^ (row & 7)) << 3); \
            unsigned short* dst = &Al[0][0] + (BUF) * 8192 \
                + ((i * 256 + (tid & 192)) << 3); \
            GLL16(src, dst); \
        } }

    #define LOADBV(DST, KT) { \
        const unsigned short* bp = bfr + (size_t)(KT) * 1024; \
        _Pragma("unroll") \
        for (int s = 0; s < 2; ++s) \
            _Pragma("unroll") \
            for (int j = 0; j < 4; ++j) \
                DST[s][j] = *(const bf16x8*)(bp + (size_t)j * 16384 + s * 512); }

    // At every barrier, only the 12 newest vmem ops (next-bv[8] + next
    // stage[4]) may remain in flight; vmcnt(12) retires everything older,
    // including the stage group for the buffer read next. Compiler auto-waits
    // can only retire more -> still correct.
    #define SYNCPOINT { \
        asm volatile("s_waitcnt vmcnt(12)" ::: "memory"); \
        __builtin_amdgcn_s_barrier(); \
        __builtin_amdgcn_sched_barrier(0); }

    #define COMPUTE(BUF, BV) { \
        _Pragma("unroll") \
        for (int s = 0; s < 2; ++s) { \
            bf16x8 av[4]; \
            _Pragma("unroll") \
            for (int m = 0; m < 4; ++m) { \
                int row  = wr * 64 + m * 16 + l15; \
                int slot = (s * 4 + l4) ^ (row & 7); \
                av[m] = *(const bf16x8*)(&Al[0][0] + (BUF) * 8192 \
                                         + row * 64 + slot * 8); \
            } \
            __builtin_amdgcn_s_setprio(1); \
            _Pragma("unroll") \
            for (int m = 0; m < 4; ++m) \
                _Pragma("unroll") \
                for (int n = 0; n < 4; ++n) \
                    acc[m][n] = __builtin_amdgcn_mfma_f32_16x16x32_bf16( \
                        av[m], BV[s][n], acc[m][n], 0, 0, 0); \
            __builtin_amdgcn_s_setprio(0); \
        } }

    // ---- prologue: stage tiles 0,1; bv(0); retire stage(0) ----
    STAGE_A(0, 0)
    STAGE_A(1, 1)
    LOADBV(bvE, 0)
    __builtin_amdgcn_sched_barrier(0);
    SYNCPOINT

    for (int u = 0; u < 8; ++u) {
        const int t  = 2 * u;
        const int c2 = (t + 2 < 16) ? t + 2 : 15;   // tail: redundant re-stage
        const int c3 = (t + 3 < 16) ? t + 3 : 15;   //  (keeps ledger uniform)

        // ---- half A: compute tile t ----
        LOADBV(bvF, t + 1)                    // bv for tile t+1
        __builtin_amdgcn_sched_barrier(0);
        STAGE_A(c2, (t + 2) % 3)              // stage tile t+2
        __builtin_amdgcn_sched_barrier(0);
        COMPUTE(t % 3, bvE)
        SYNCPOINT                             // retires stage(t+1)

        // ---- half B: compute tile t+1 ----
        LOADBV(bvE, c2)                       // bv for tile t+2
        __builtin_amdgcn_sched_barrier(0);
        STAGE_A(c3, (t + 3) % 3)              // stage tile t+3
        __builtin_amdgcn_sched_barrier(0);
        COMPUTE((t + 1) % 3, bvF)
        SYNCPOINT                             // retires stage(t+2)
    }
    #undef STAGE_A
    #undef LOADBV
    #undef SYNCPOINT
    #undef COMPUTE

    // ---- epilogue: C/D layout (m89): col = lane&15, row = (lane>>4)*4 + reg
    const int colb = n0 + wc * 64 + l15;
    #pragma unroll
    for (int m = 0; m < 4; ++m) {
        const int trow0 = t0 + wr * 64 + m * 16 + (l4 << 2);
        #pragma unroll
        for (int r = 0; r < 4; ++r) {
            const int t = trow0 + r;
            if (t > 4096) continue;   // tail tile: only valid frames
            const size_t rowbase = (size_t)batch * (NFRAMES * 512) + (size_t)t * 512;
            #pragma unroll
            for (int n = 0; n < 4; ++n) {
                const int gc = colb + n * 16;
                const size_t o = (size_t)(gc >> 9) * HALF_SZ + rowbase + (gc & 511);
                out[o] = acc[m][n][r];
            }
        }
    }
}

// ===========================================================================
// Fallback path (round-2 kernels, proven pass) — used only if ws too small.
// ===========================================================================
#define BM 128
#define BN 128
#define BK 64
#define LDPAD 72

__global__ void basis_transpose_fb(const float* __restrict__ basis,
                                   unsigned short* __restrict__ Bt) {
    __shared__ float L[64][65];
    const int kt  = blockIdx.x & 15;
    const int nt  = blockIdx.x >> 4;
    const int tid = threadIdx.x;
    const int colbase = nt * 64 + (nt < 8 ? 1 : 2);
    #pragma unroll
    for (int i = 0; i < 16; ++i) {
        int r = i * 4 + (tid >> 6);
        int c = tid & 63;
        L[r][c] = basis[(size_t)(kt * 64 + r) * BASIS_LD + colbase + c];
    }
    __syncthreads();
    #pragma unroll
    for (int i = 0; i < 16; ++i) {
        int n = i * 4 + (tid >> 6);
        int k = tid & 63;
        Bt[(size_t)(nt * 64 + n) * 1024 + kt * 64 + k] = f2bf(L[k][n]);
    }
}

__global__ __launch_bounds__(256, 2) void stft_gemm_fb(
    const float* __restrict__ x,
    const unsigned short* __restrict__ Bt,
    float* __restrict__ out)
{
    __shared__ unsigned short Al[BM * LDPAD];
    __shared__ unsigned short Bl[BN * LDPAD];
    const int bid = blockIdx.x;
    const int wg  = (bid & 7) * (GRID / 8) + (bid >> 3);
    const int ntile = wg & 7;
    const int mtile = (wg >> 3) % MTILES;
    const int batch = wg / (MTILES * NTILES);
    const int tid  = threadIdx.x;
    const int lane = tid & 63;
    const int wid  = tid >> 6;
    const int wr   = wid >> 1;
    const int wc   = wid & 1;
    const int t0 = mtile * BM;
    const int n0 = ntile * BN;
    const float* __restrict__ xb = x + (size_t)batch * NX;

    f32x4 acc[4][4];
    #pragma unroll
    for (int m = 0; m < 4; ++m)
        #pragma unroll
        for (int n = 0; n < 4; ++n)
            acc[m][n] = (f32x4)0.0f;

    for (int k0 = 0; k0 < KDIM; k0 += BK) {
        #pragma unroll
        for (int it = 0; it < 8; ++it) {
            int idx = it * 256 + tid;
            int row = idx >> 4;
            int c4  = idx & 15;
            int t   = t0 + row;
            float v0, v1, v2, v3;
            int j = t * 512 + k0 + c4 * 4 - 512;
            if (t <= 4096) {
                if (j >= 0 && j + 3 < NX) {
                    const float4 f = *(const float4*)(xb + j);
                    v0 = f.x; v1 = f.y; v2 = f.z; v3 = f.w;
                } else {
                    float vv[4];
                    #pragma unroll
                    for (int e = 0; e < 4; ++e) {
                        int jj = j + e;
                        if (jj < 0) jj = -jj;
                        else if (jj >= NX) jj = 2 * (NX - 1) - jj;
                        vv[e] = xb[jj];
                    }
                    v0 = vv[0]; v1 = vv[1]; v2 = vv[2]; v3 = vv[3];
                }
            } else {
                v0 = v1 = v2 = v3 = 0.0f;
            }
            union { unsigned short s[4]; uint32_t u[2]; } p;
            p.s[0] = f2bf(v0); p.s[1] = f2bf(v1);
            p.s[2] = f2bf(v2); p.s[3] = f2bf(v3);
            *(uint32_t*)(Al + row * LDPAD + c4 * 4)     = p.u[0];
            *(uint32_t*)(Al + row * LDPAD + c4 * 4 + 2) = p.u[1];
        }
        #pragma unroll
        for (int it = 0; it < 4; ++it) {
            int idx = it * 256 + tid;
            int n  = idx >> 3;
            int kc = idx & 7;
            uint4 v = *(const uint4*)(Bt + (size_t)(n0 + n) * 1024 + k0 + kc * 8);
            *(uint4*)(Bl + n * LDPAD + kc * 8) = v;
        }
        __syncthreads();
        #pragma unroll
        for (int ks = 0; ks < 2; ++ks) {
            bf16x8 af[4], bfr[4];
            #pragma unroll
            for (int m = 0; m < 4; ++m)
                af[m] = *(const bf16x8*)(Al + (wr * 64 + m * 16 + (lane & 15)) * LDPAD
                                            + ks * 32 + (lane >> 4) * 8);
            #pragma unroll
            for (int n = 0; n < 4; ++n)
                bfr[n] = *(const bf16x8*)(Bl + (wc * 64 + n * 16 + (lane & 15)) * LDPAD
                                             + ks * 32 + (lane >> 4) * 8);
            #pragma unroll
            for (int m = 0; m < 4; ++m)
                #pragma unroll
                for (int n = 0; n < 4; ++n)
                    acc[m][n] = __builtin_amdgcn_mfma_f32_16x16x32_bf16(
                        af[m], bfr[n], acc[m][n], 0, 0, 0);
        }
        __syncthreads();
    }
    const int colb = n0 + wc * 64 + (lane & 15);
    #pragma unroll
    for (int m = 0; m < 4; ++m) {
        const int trow0 = t0 + wr * 64 + m * 16 + ((lane >> 4) << 2);
        #pragma unroll
        for (int r = 0; r < 4; ++r) {
            const int t = trow0 + r;
            if (t > 4096) continue;
            const size_t rowbase = (size_t)batch * (NFRAMES * 512) + (size_t)t * 512;
            #pragma unroll
            for (int n = 0; n < 4; ++n) {
                const int gc = colb + n * 16;
                const size_t o = (size_t)(gc >> 9) * HALF_SZ + rowbase + (gc & 511);
                out[o] = acc[m][n][r];
            }
        }
    }
}

extern "C" void kernel_launch(void* const* d_in, const int* in_sizes, int n_in,
                              void* d_out, int out_size, void* d_ws, size_t ws_size,
                              hipStream_t stream) {
    const float* x     = (const float*)d_in[0];
    const float* basis = (const float*)d_in[1];
    float* out = (float*)d_out;

    if (ws_size >= WS_NEEDED) {
        unsigned short* xp    = (unsigned short*)d_ws;
        unsigned short* Bfrag = (unsigned short*)((char*)d_ws + BFRAG_OFF);
        convert_pad<<<(NBATCH * (PADLEN >> 2)) / 256, 256, 0, stream>>>(x, xp);
        basis_to_frag<<<512, 256, 0, stream>>>(basis, Bfrag);
        stft_gemm7<<<GRID, 256, 0, stream>>>(xp, Bfrag, out);
    } else {
        unsigned short* Bt = (unsigned short*)d_ws;
        basis_transpose_fb<<<256, 256, 0, stream>>>(basis, Bt);
        stft_gemm_fb<<<GRID, 256, 0, stream>>>(x, Bt, out);
    }
}

// Round 10
// 145.810 us; speedup vs baseline: 1.0639x; 1.0639x over previous
//
#include <hip/hip_runtime.h>
#include <hip/hip_bf16.h>
#include <stdint.h>

// STFT as GEMM:  C[b,t,n] = sum_k frames[b,t,k] * basis[k, col(n)]
//   frames[b,t,k] = reflect_pad(x[b])[t*512 + k]   (pad 512 both sides)
//   col(n) = n+1 for n<512 (re half), n+2 for n>=512 (im half)
// Output: d_out = [re (8*4097*512) | im (8*4097*512)] fp32.
//
// v9 = v4's PASSING 256x256 8-wave skeleton with the two diagnosed fixes:
//   1) grid 512 (= exactly 2 blocks/CU rounds; frames 0..4095) + tail_frame
//      GEMV kernel for frame 4096  (v4's 544 grid = 3 rounds, 29% straggler)
//   2) ks-split balanced phases: each phase = {4-8 ds_read_b128; stage one
//      half-tile; barrier; 16 MFMA; barrier}; reads 8/4/8/4 (v4 was 12/4/8/0)
//   Stage order re-derived for new liveness: ph0 A0(t+1), ph1 A1(t+1),
//   ph2 B1(t+1), ph3 B0(t+2)->cur (B0 region of cur last read at ph2).
//   Per-wave vmcnt ledger at boundary: 10 outstanding -> vmcnt(2) keeps only
//   B0(t+2) in flight. In-loop vmem ops = GLL16 only (B frags via LDS), so
//   the ledger is exact. No register arrays beyond v4's budget (no spill).

#define NX       2097152
#define NFRAMES  4097
#define NBATCH   8
#define KDIM     1024
#define BASIS_LD 1026
#define HALF_SZ  (NBATCH * NFRAMES * 512)

#define PADLEN   2163712   // 4224*512 + 1024, per batch
#define XP_BYTES ((size_t)NBATCH * PADLEN * 2)
#define BIMG_OFF XP_BYTES
#define BIMG_BYTES ((size_t)4 * 16 * 16384 * 2)   // 2 MB
#define WS_NEEDED (BIMG_OFF + BIMG_BYTES)

#define MTILES8 16
#define NTILES8 4
#define GRID8   (NBATCH * MTILES8 * NTILES8)   // 512 = exactly 2 rounds of 256 CUs

typedef __attribute__((ext_vector_type(8))) short bf16x8;
typedef __attribute__((ext_vector_type(4))) float f32x4;

#define GLL16(src, dst) __builtin_amdgcn_global_load_lds( \
    (const __attribute__((address_space(1))) unsigned int*)(src), \
    (__attribute__((address_space(3))) unsigned int*)(dst), 16, 0, 0)

static __device__ __forceinline__ unsigned short f2bf(float f) {
    union { float f; uint32_t u; } v; v.f = f;
    uint32_t r = (v.u + 0x7FFFu + ((v.u >> 16) & 1u)) >> 16;  // RNE
    return (unsigned short)r;
}

// ---------------------------------------------------------------------------
// Kernel 0: x fp32 -> reflect-padded bf16 xp (per-batch PADLEN elems).
// ---------------------------------------------------------------------------
__global__ void convert_pad(const float* __restrict__ x,
                            unsigned short* __restrict__ xp) {
    const int per = PADLEN >> 2;
    int gid = blockIdx.x * 256 + threadIdx.x;
    int b   = gid / per;
    int i4  = (gid - b * per) << 2;
    const float* xb = x + (size_t)b * NX;
    int j = i4 - 512;
    unsigned short s0, s1, s2, s3;
    if (j >= 0 && j + 3 < NX) {
        float4 f = *(const float4*)(xb + j);
        s0 = f2bf(f.x); s1 = f2bf(f.y); s2 = f2bf(f.z); s3 = f2bf(f.w);
    } else {
        unsigned short ss[4];
        #pragma unroll
        for (int e = 0; e < 4; ++e) {
            int i = i4 + e;
            float v = 0.0f;
            if (i < NX + 1024) {
                int jj = i - 512;
                if (jj < 0) jj = -jj;
                else if (jj >= NX) jj = 2 * (NX - 1) - jj;
                v = xb[jj];
            }
            ss[e] = f2bf(v);
        }
        s0 = ss[0]; s1 = ss[1]; s2 = ss[2]; s3 = ss[3];
    }
    union { unsigned short s[4]; uint2 u; } p;
    p.s[0] = s0; p.s[1] = s1; p.s[2] = s2; p.s[3] = s3;
    *(uint2*)(xp + (size_t)b * PADLEN + i4) = p.u;
}

// ---------------------------------------------------------------------------
// Kernel 1: basis -> Bimg [nt2(4)][kt(16)][row(256)][slot(8)][8 bf16],
// slot = (k_local>>3) ^ (row&7): pre-swizzled for linear global_load_lds.
// (v4 verbatim — refcheck-passed.)
// ---------------------------------------------------------------------------
__global__ void basis_to_img(const float* __restrict__ basis,
                             unsigned short* __restrict__ Bimg) {
    __shared__ float L[64][65];
    const int kt  = blockIdx.x & 15;      // 64-wide k tile
    const int nt  = blockIdx.x >> 4;      // 64-wide n tile (0..15)
    const int tid = threadIdx.x;
    const int colbase = nt * 64 + (nt < 8 ? 1 : 2);   // re/im column select
    #pragma unroll
    for (int i = 0; i < 16; ++i) {
        int r = i * 4 + (tid >> 6);
        int c = tid & 63;
        L[r][c] = basis[(size_t)(kt * 64 + r) * BASIS_LD + colbase + c];
    }
    __syncthreads();
    #pragma unroll
    for (int i = 0; i < 16; ++i) {
        int nl = i * 4 + (tid >> 6);
        int kk = tid & 63;
        int n  = nt * 64 + nl;
        int nt2 = n >> 8, row = n & 255;
        int dslot = (kk >> 3) ^ (row & 7);
        size_t off = ((size_t)(nt2 * 16 + kt) * 256 + row) * 64 + dslot * 8 + (kk & 7);
        Bimg[off] = f2bf(L[kk][nl]);
    }
}

// ---------------------------------------------------------------------------
// Kernel 2: tail frame t=4096 (per batch): 8x1024 outputs, K=1024 GEMV.
// ---------------------------------------------------------------------------
__global__ void tail_frame(const unsigned short* __restrict__ xp,
                           const float* __restrict__ basis,
                           float* __restrict__ out) {
    __shared__ float fr[1024];
    const int b = blockIdx.x >> 2, chunk = blockIdx.x & 3;
    const int tid = threadIdx.x;
    #pragma unroll
    for (int i = 0; i < 4; ++i) {
        unsigned short u = xp[(size_t)b * PADLEN + 4096 * 512 + i * 256 + tid];
        union { uint32_t u; float f; } c; c.u = ((uint32_t)u) << 16;
        fr[i * 256 + tid] = c.f;
    }
    __syncthreads();
    const int n = chunk * 256 + tid;
    const int col = n + 1 + (n >= 512);
    float s = 0.0f;
    #pragma unroll 8
    for (int k = 0; k < 1024; ++k)
        s += fr[k] * basis[(size_t)k * BASIS_LD + col];
    const size_t rowbase = (size_t)b * (NFRAMES * 512) + (size_t)4096 * 512;
    out[(size_t)(n >> 9) * HALF_SZ + rowbase + (n & 511)] = s;
}

// ---------------------------------------------------------------------------
// Kernel 3: 256x256 8-wave bf16 MFMA GEMM, balanced ks-split phases.
// Half-tiles: 0=A rows 0-127, 1=A rows 128-255, 2=B rows 0-127, 3=B 128-255.
// ---------------------------------------------------------------------------
__device__ __forceinline__ void stage_half(
    int hid, int kt, int bufoff,
    const unsigned short* xpb, int t0, const unsigned short* bnt,
    unsigned short* Al, unsigned short* Bl, int tid)
{
    #pragma unroll
    for (int ld = 0; ld < 2; ++ld) {
        int q = ld * 512 + tid;
        if (hid < 2) {
            int row = q >> 3, d = q & 7;
            const unsigned short* src = xpb
                + (size_t)(t0 + hid * 128 + row) * 512
                + kt * 64 + ((d ^ (row & 7)) << 3);
            unsigned short* dst = Al + bufoff + hid * 8192
                + ((ld * 512 + (tid & 448)) << 3);
            GLL16(src, dst);
        } else {
            const unsigned short* src = bnt + kt * 16384 + (hid - 2) * 8192 + (q << 3);
            unsigned short* dst = Bl + bufoff + (hid - 2) * 8192
                + ((ld * 512 + (tid & 448)) << 3);
            GLL16(src, dst);
        }
    }
}

__global__ __launch_bounds__(512, 2) void stft_gemm8(
    const unsigned short* __restrict__ xp,
    const unsigned short* __restrict__ Bimg,
    float* __restrict__ out)
{
    __shared__ unsigned short Al[2 * 256 * 64];   // 64 KB, dbuf
    __shared__ unsigned short Bl[2 * 256 * 64];   // 64 KB, dbuf

    const int bid = blockIdx.x;
    const int wg  = (bid & 7) * (GRID8 / 8) + (bid >> 3);  // bijective XCD swizzle
    const int ntile = wg & 3;
    const int mtile = (wg >> 2) & 15;
    const int batch = wg >> 6;

    const int tid  = threadIdx.x;
    const int lane = tid & 63;
    const int wid  = tid >> 6;
    const int wm   = wid >> 2;          // 0..1 -> 128-row band
    const int wn   = wid & 3;           // 0..3 -> 64-col band
    const int t0   = mtile * 256;       // frames 0..4095 (4096 -> tail_frame)
    const int n0   = ntile * 256;

    const unsigned short* __restrict__ xpb = xp + (size_t)batch * PADLEN;
    const unsigned short* __restrict__ bnt = Bimg + (size_t)ntile * 16 * 16384;

    const int l15 = lane & 15, l4 = lane >> 4;
    const int arow0 = wm * 128 + l15;
    const int brow0 = wn * 64 + l15;

    f32x4 acc[8][4];
    #pragma unroll
    for (int m = 0; m < 8; ++m)
        #pragma unroll
        for (int n = 0; n < 4; ++n)
            acc[m][n] = (f32x4)0.0f;

    bf16x8 a[4];   // current phase A frags
    bf16x8 b[4];   // current ks B frags (reloaded at ks switch)

    #define LOAD_A(G, KS) { \
        _Pragma("unroll") \
        for (int m = 0; m < 4; ++m) { \
            int row  = arow0 + (G) * 64 + m * 16; \
            int slot = ((KS) * 4 + l4) ^ (row & 7); \
            a[m] = *(const bf16x8*)(Al + cur + row * 64 + slot * 8); \
        } }
    #define LOAD_B(KS) { \
        _Pragma("unroll") \
        for (int n = 0; n < 4; ++n) { \
            int row  = brow0 + n * 16; \
            int slot = ((KS) * 4 + l4) ^ (row & 7); \
            b[n] = *(const bf16x8*)(Bl + cur + row * 64 + slot * 8); \
        } }
    #define MFMA_CLUSTER(G) \
        __builtin_amdgcn_s_setprio(1); \
        _Pragma("unroll") \
        for (int m = 0; m < 4; ++m) { \
            _Pragma("unroll") \
            for (int n = 0; n < 4; ++n) \
                acc[(G) * 4 + m][n] = __builtin_amdgcn_mfma_f32_16x16x32_bf16( \
                    a[m], b[n], acc[(G) * 4 + m][n], 0, 0, 0); \
        } \
        __builtin_amdgcn_s_setprio(0);

    // ---- prologue: tile0 all 4 halves + B0(1); retire tile0 (vmcnt(2)) ----
    stage_half(0, 0, 0,     xpb, t0, bnt, Al, Bl, tid);
    stage_half(1, 0, 0,     xpb, t0, bnt, Al, Bl, tid);
    stage_half(3, 0, 0,     xpb, t0, bnt, Al, Bl, tid);
    stage_half(2, 0, 0,     xpb, t0, bnt, Al, Bl, tid);
    stage_half(2, 1, 16384, xpb, t0, bnt, Al, Bl, tid);   // B0(1) -> buf1
    asm volatile("s_waitcnt vmcnt(2)" ::: "memory");
    __builtin_amdgcn_s_barrier();
    __builtin_amdgcn_sched_barrier(0);

    // Steady-state per-wave ledger at each tile boundary (in-order retire):
    //   in flight: B0(t+1)@ph3(t-1), A0(t+1)@ph0, A1(t+1)@ph1, B1(t+1)@ph2,
    //              B0(t+2)@ph3  (2 GLL16 each, 10 total)
    //   vmcnt(2) retires all of tile t+1's halves; keeps B0(t+2) in flight.
    for (int t = 0; t < 16; ++t) {
        const int cur = (t & 1) << 14;       // 16384-elem buffer offset
        const int nxt = cur ^ 16384;
        const int ktn  = (t + 1 < 16) ? t + 1 : 15;   // tail: redundant re-stage
        const int ktn2 = (t + 2 < 16) ? t + 2 : 15;   // (keeps ledger uniform)

        // ---- phase 0: read a(G0,ks0)+b(ks0) [8]; stage A0(t+1) ----
        LOAD_A(0, 0)
        LOAD_B(0)
        stage_half(0, ktn, nxt, xpb, t0, bnt, Al, Bl, tid);
        __builtin_amdgcn_s_barrier();
        MFMA_CLUSTER(0)
        __builtin_amdgcn_s_barrier();

        // ---- phase 1: read a(G1,ks0) [4]; stage A1(t+1) ----
        LOAD_A(1, 0)
        stage_half(1, ktn, nxt, xpb, t0, bnt, Al, Bl, tid);
        __builtin_amdgcn_s_barrier();
        MFMA_CLUSTER(1)
        __builtin_amdgcn_s_barrier();

        // ---- phase 2: read a(G0,ks1)+b(ks1) [8]; stage B1(t+1) ----
        LOAD_A(0, 1)
        LOAD_B(1)
        stage_half(3, ktn, nxt, xpb, t0, bnt, Al, Bl, tid);
        __builtin_amdgcn_s_barrier();
        MFMA_CLUSTER(0)
        __builtin_amdgcn_s_barrier();

        // ---- phase 3: read a(G1,ks1) [4]; stage B0(t+2) into cur (B0-cur
        //      last read in phase 2); boundary counted vmcnt(2). ----
        LOAD_A(1, 1)
        stage_half(2, ktn2, cur, xpb, t0, bnt, Al, Bl, tid);
        __builtin_amdgcn_s_barrier();
        MFMA_CLUSTER(1)
        asm volatile("s_waitcnt vmcnt(2)" ::: "memory");
        __builtin_amdgcn_s_barrier();
        __builtin_amdgcn_sched_barrier(0);
    }
    #undef LOAD_A
    #undef LOAD_B
    #undef MFMA_CLUSTER

    // ---- epilogue: C/D layout (m89): col = lane&15, row = (lane>>4)*4 + reg
    #pragma unroll
    for (int m = 0; m < 8; ++m) {
        const int trow0 = t0 + wm * 128 + m * 16 + (l4 << 2);
        #pragma unroll
        for (int r = 0; r < 4; ++r) {
            const int tf = trow0 + r;   // always <= 4095
            const size_t rowbase = (size_t)batch * (NFRAMES * 512) + (size_t)tf * 512;
            #pragma unroll
            for (int n = 0; n < 4; ++n) {
                const int gc = n0 + wn * 64 + n * 16 + l15;
                const size_t o = (size_t)(gc >> 9) * HALF_SZ + rowbase + (gc & 511);
                out[o] = acc[m][n][r];
            }
        }
    }
}

// ===========================================================================
// Fallback path (round-2 kernels, proven pass) — used only if ws too small.
// ===========================================================================
#define BM 128
#define BN 128
#define BK 64
#define LDPAD 72
#define MTILES 33
#define NTILES 8
#define GRID   (NBATCH * MTILES * NTILES)

__global__ void basis_transpose_fb(const float* __restrict__ basis,
                                   unsigned short* __restrict__ Bt) {
    __shared__ float L[64][65];
    const int kt  = blockIdx.x & 15;
    const int nt  = blockIdx.x >> 4;
    const int tid = threadIdx.x;
    const int colbase = nt * 64 + (nt < 8 ? 1 : 2);
    #pragma unroll
    for (int i = 0; i < 16; ++i) {
        int r = i * 4 + (tid >> 6);
        int c = tid & 63;
        L[r][c] = basis[(size_t)(kt * 64 + r) * BASIS_LD + colbase + c];
    }
    __syncthreads();
    #pragma unroll
    for (int i = 0; i < 16; ++i) {
        int n = i * 4 + (tid >> 6);
        int k = tid & 63;
        Bt[(size_t)(nt * 64 + n) * 1024 + kt * 64 + k] = f2bf(L[k][n]);
    }
}

__global__ __launch_bounds__(256, 2) void stft_gemm_fb(
    const float* __restrict__ x,
    const unsigned short* __restrict__ Bt,
    float* __restrict__ out)
{
    __shared__ unsigned short Al[BM * LDPAD];
    __shared__ unsigned short Bl[BN * LDPAD];
    const int bid = blockIdx.x;
    const int wg  = (bid & 7) * (GRID / 8) + (bid >> 3);
    const int ntile = wg & 7;
    const int mtile = (wg >> 3) % MTILES;
    const int batch = wg / (MTILES * NTILES);
    const int tid  = threadIdx.x;
    const int lane = tid & 63;
    const int wid  = tid >> 6;
    const int wr   = wid >> 1;
    const int wc   = wid & 1;
    const int t0 = mtile * BM;
    const int n0 = ntile * BN;
    const float* __restrict__ xb = x + (size_t)batch * NX;

    f32x4 acc[4][4];
    #pragma unroll
    for (int m = 0; m < 4; ++m)
        #pragma unroll
        for (int n = 0; n < 4; ++n)
            acc[m][n] = (f32x4)0.0f;

    for (int k0 = 0; k0 < KDIM; k0 += BK) {
        #pragma unroll
        for (int it = 0; it < 8; ++it) {
            int idx = it * 256 + tid;
            int row = idx >> 4;
            int c4  = idx & 15;
            int t   = t0 + row;
            float v0, v1, v2, v3;
            int j = t * 512 + k0 + c4 * 4 - 512;
            if (t <= 4096) {
                if (j >= 0 && j + 3 < NX) {
                    const float4 f = *(const float4*)(xb + j);
                    v0 = f.x; v1 = f.y; v2 = f.z; v3 = f.w;
                } else {
                    float vv[4];
                    #pragma unroll
                    for (int e = 0; e < 4; ++e) {
                        int jj = j + e;
                        if (jj < 0) jj = -jj;
                        else if (jj >= NX) jj = 2 * (NX - 1) - jj;
                        vv[e] = xb[jj];
                    }
                    v0 = vv[0]; v1 = vv[1]; v2 = vv[2]; v3 = vv[3];
                }
            } else {
                v0 = v1 = v2 = v3 = 0.0f;
            }
            union { unsigned short s[4]; uint32_t u[2]; } p;
            p.s[0] = f2bf(v0); p.s[1] = f2bf(v1);
            p.s[2] = f2bf(v2); p.s[3] = f2bf(v3);
            *(uint32_t*)(Al + row * LDPAD + c4 * 4)     = p.u[0];
            *(uint32_t*)(Al + row * LDPAD + c4 * 4 + 2) = p.u[1];
        }
        #pragma unroll
        for (int it = 0; it < 4; ++it) {
            int idx = it * 256 + tid;
            int n  = idx >> 3;
            int kc = idx & 7;
            uint4 v = *(const uint4*)(Bt + (size_t)(n0 + n) * 1024 + k0 + kc * 8);
            *(uint4*)(Bl + n * LDPAD + kc * 8) = v;
        }
        __syncthreads();
        #pragma unroll
        for (int ks = 0; ks < 2; ++ks) {
            bf16x8 af[4], bfr[4];
            #pragma unroll
            for (int m = 0; m < 4; ++m)
                af[m] = *(const bf16x8*)(Al + (wr * 64 + m * 16 + (lane & 15)) * LDPAD
                                            + ks * 32 + (lane >> 4) * 8);
            #pragma unroll
            for (int n = 0; n < 4; ++n)
                bfr[n] = *(const bf16x8*)(Bl + (wc * 64 + n * 16 + (lane & 15)) * LDPAD
                                             + ks * 32 + (lane >> 4) * 8);
            #pragma unroll
            for (int m = 0; m < 4; ++m)
                #pragma unroll
                for (int n = 0; n < 4; ++n)
                    acc[m][n] = __builtin_amdgcn_mfma_f32_16x16x32_bf16(
                        af[m], bfr[n], acc[m][n], 0, 0, 0);
        }
        __syncthreads();
    }
    const int colb = n0 + wc * 64 + (lane & 15);
    #pragma unroll
    for (int m = 0; m < 4; ++m) {
        const int trow0 = t0 + wr * 64 + m * 16 + ((lane >> 4) << 2);
        #pragma unroll
        for (int r = 0; r < 4; ++r) {
            const int t = trow0 + r;
            if (t > 4096) continue;
            const size_t rowbase = (size_t)batch * (NFRAMES * 512) + (size_t)t * 512;
            #pragma unroll
            for (int n = 0; n < 4; ++n) {
                const int gc = colb + n * 16;
                const size_t o = (size_t)(gc >> 9) * HALF_SZ + rowbase + (gc & 511);
                out[o] = acc[m][n][r];
            }
        }
    }
}

extern "C" void kernel_launch(void* const* d_in, const int* in_sizes, int n_in,
                              void* d_out, int out_size, void* d_ws, size_t ws_size,
                              hipStream_t stream) {
    const float* x     = (const float*)d_in[0];
    const float* basis = (const float*)d_in[1];
    float* out = (float*)d_out;

    if (ws_size >= WS_NEEDED) {
        unsigned short* xp   = (unsigned short*)d_ws;
        unsigned short* Bimg = (unsigned short*)((char*)d_ws + BIMG_OFF);
        convert_pad<<<(NBATCH * (PADLEN >> 2)) / 256, 256, 0, stream>>>(x, xp);
        basis_to_img<<<256, 256, 0, stream>>>(basis, Bimg);
        tail_frame<<<32, 256, 0, stream>>>(xp, basis, out);
        stft_gemm8<<<GRID8, 512, 0, stream>>>(xp, Bimg, out);
    } else {
        unsigned short* Bt = (unsigned short*)d_ws;
        basis_transpose_fb<<<256, 256, 0, stream>>>(basis, Bt);
        stft_gemm_fb<<<GRID, 256, 0, stream>>>(x, Bt, out);
    }
}

// Round 12
// 88.233 us; speedup vs baseline: 1.7582x; 1.6526x over previous
//
#include <hip/hip_runtime.h>
#include <hip/hip_bf16.h>
#include <stdint.h>

// STFT as GEMM with DFT symmetry fold (v11 = v10 with 3 bug fixes):
//   re[t,n] = sum_{k=0..1023} w[k]f[k] cos(2pi k(n+1)/1024)
//   im[t,n] = -sum_k w[k]f[k] sin(2pi k(n+1)/1024)
//   cos even / sin odd under k->1024-k, w symmetric, sin(512*theta)=0 =>
//   with UNWINDOWED folds u[k]=f[k]+f[1024-k], v[k]=f[k]-f[1024-k] (k=1..511),
//   u[512]=f[512], v[512]=0:
//     re[t,n] = 0.08*f[0] + sum_{k=1..512} u[k]*basis[k][n+1]
//     im[t,n] =             sum_{k=1..512} v[k]*basis[k][514+n]
//   (basis already contains w -> fold must NOT apply w again; v10 bug #2)
//   => two K=512 GEMMs (half the FLOPs), v3-proven MFMA structure.
// Fixes vs v10: (1) fold_pad both-edge reflect (OOB page fault -> hang),
// (2) no double-window, (3) tier-2 basis_to_img offset restored to round-4.
// Output: d_out = [re (8*4097*512) | im (8*4097*512)] fp32.

#define NX       2097152
#define NFRAMES  4097
#define NBATCH   8
#define KDIM     1024
#define BASIS_LD 1026
#define HALF_SZ  (NBATCH * NFRAMES * 512)

typedef __attribute__((ext_vector_type(8))) short bf16x8;
typedef __attribute__((ext_vector_type(4))) float f32x4;

#define GLL16(src, dst) __builtin_amdgcn_global_load_lds( \
    (const __attribute__((address_space(1))) unsigned int*)(src), \
    (__attribute__((address_space(3))) unsigned int*)(dst), 16, 0, 0)

static __device__ __forceinline__ unsigned short f2bf(float f) {
    union { float f; uint32_t u; } v; v.f = f;
    uint32_t r = (v.u + 0x7FFFu + ((v.u >> 16) & 1u)) >> 16;  // RNE
    return (unsigned short)r;
}

static __device__ __forceinline__ int refl(int i) {
    if (i < 0) return -i;
    if (i >= NX) return 2 * (NX - 1) - i;
    return i;
}

// ======================= Tier-1 (symmetry-folded) ==========================
// ws layout: uv | Bimg2 | g0t
#define UV_BYTES    ((size_t)NBATCH * NFRAMES * 1024 * 2)        // 67,125,248
#define BIMG2_OFF   UV_BYTES
#define BIMG2_BYTES ((size_t)8 * 8 * 128 * 64 * 2)               // 1 MB
#define G0_OFF      (BIMG2_OFF + BIMG2_BYTES)
#define G0_BYTES    ((size_t)NBATCH * NFRAMES * 4)
#define WS_NEEDED2  (G0_OFF + G0_BYTES)

#define MTILES 33
#define NTILES 8
#define GRID   (NBATCH * MTILES * NTILES)  // 2112 = 8 * 264

// Kernel: g0t[b][t] = 0.08 * f[0] = w[0]*padded[t*512]  (fp32 exact)
__global__ void g0_fill(const float* __restrict__ x, float* __restrict__ g0t) {
    int idx = blockIdx.x * 256 + threadIdx.x;
    if (idx >= NBATCH * NFRAMES) return;
    int b = idx / NFRAMES, t = idx - b * NFRAMES;
    g0t[idx] = 0.08f * x[(size_t)b * NX + refl(t * 512 - 512)];
}

// Kernel: fold_pad — per (b,t): unwindowed u,v rows (bf16), reflect both edges.
//   uv[(b*4097+t)*1024 + (k-1)]       = u[k] = f[k]+f[1024-k]   k=1..512
//   uv[(b*4097+t)*1024 + 512 + (k-1)] = v[k] = f[k]-f[1024-k]
//   (u[512]=f[512] single term; v[512]=0 naturally since idx coincide)
__global__ void fold_pad(const float* __restrict__ x,
                         unsigned short* __restrict__ uv) {
    const int blk = blockIdx.x;              // 0 .. 8*4097-1
    const int b = blk / NFRAMES, t = blk - b * NFRAMES;
    const int tid = threadIdx.x;
    const float* xb = x + (size_t)b * NX;
    const int t512 = t * 512;
    const int k1 = 2 * tid + 1, k2 = k1 + 1;          // 1..511 / 2..512
    const int p1a = refl(t512 + k1 - 512);            // f[k1]
    const int p1b = refl(t512 + k2 - 512);            // f[k2]
    const int p2a = refl(t512 + 512 - k1);            // f[1024-k1]
    const int p2b = refl(t512 + 512 - k2);            // f[1024-k2]
    float x1a = xb[p1a], x1b = xb[p1b], x2a = xb[p2a], x2b = xb[p2b];
    float u1 = x1a + x2a;
    float v1 = x1a - x2a;
    float u2 = (k2 == 512) ? x1b : (x1b + x2b);       // k=512 appears once
    float v2 = x1b - x2b;                             // = 0 at k2==512
    union { unsigned short s[2]; uint32_t u; } pu, pv;
    pu.s[0] = f2bf(u1); pu.s[1] = f2bf(u2);
    pv.s[0] = f2bf(v1); pv.s[1] = f2bf(v2);
    unsigned short* row = uv + (size_t)blk * 1024;
    *(uint32_t*)(row + 2 * tid)       = pu.u;
    *(uint32_t*)(row + 512 + 2 * tid) = pv.u;
}

// Kernel: basis rows 1..512 -> Bimg2 [nt2(8)][kt(8)][row(128)][slot(8)][8],
// slot = (klocal>>3) ^ (row&7): pre-swizzled for linear global_load_lds.
// Stores the TRUE basis (incl. window) — fold is unwindowed.
__global__ void basis_to_img2(const float* __restrict__ basis,
                              unsigned short* __restrict__ Bimg2) {
    __shared__ float L[64][65];
    const int kt   = blockIdx.x & 7;      // 64-wide k tile (k = 1+kt*64+r)
    const int nt64 = blockIdx.x >> 3;     // 64-wide n tile (0..15)
    const int tid  = threadIdx.x;
    const int colbase = nt64 * 64 + (nt64 < 8 ? 1 : 2);  // re: +1, im: +2
    #pragma unroll
    for (int i = 0; i < 16; ++i) {
        int r = i * 4 + (tid >> 6);       // k-local
        int c = tid & 63;
        L[r][c] = basis[(size_t)(kt * 64 + r + 1) * BASIS_LD + colbase + c];
    }
    __syncthreads();
    #pragma unroll
    for (int i = 0; i < 16; ++i) {
        int nl  = i * 4 + (tid >> 6);
        int kkl = tid & 63;
        int gn  = nt64 * 64 + nl;         // 0..1023 (re 0..511 | im 512..1023)
        int nt2 = gn >> 7, row = gn & 127;
        int dslot = (kkl >> 3) ^ (row & 7);
        size_t off = ((size_t)(nt2 * 8 + kt) * 128 + row) * 64 + dslot * 8 + (kkl & 7);
        Bimg2[off] = f2bf(L[kkl][nl]);
    }
}

// Kernel: K=512 GEMM, v3 structure verbatim (single-buffered, GLL16 + XOR
// chunk swizzle, 2 barriers/K-tile, 4 blocks/CU). ntile<4: re (u half),
// ntile>=4: im (v half). g0 added in epilogue for re.
__global__ __launch_bounds__(256, 4) void stft_gemm9(
    const unsigned short* __restrict__ uv,
    const unsigned short* __restrict__ Bimg2,
    const float* __restrict__ g0t,
    float* __restrict__ out)
{
    __shared__ unsigned short Al[128 * 64];  // 16 KB
    __shared__ unsigned short Bl[128 * 64];  // 16 KB

    const int bid = blockIdx.x;
    const int wg  = (bid & 7) * (GRID / 8) + (bid >> 3);   // bijective XCD swizzle
    const int ntile = wg & 7;
    const int mtile = (wg >> 3) % MTILES;
    const int batch = wg / (MTILES * NTILES);

    const int tid  = threadIdx.x;
    const int lane = tid & 63;
    const int wr   = tid >> 7;
    const int wc   = (tid >> 6) & 1;
    const int t0   = mtile * 128;
    const int ih   = (ntile >= 4);            // 0=re(u), 1=im(v)
    const int nh0  = (ntile & 3) * 128;       // col origin within half

    const unsigned short* __restrict__ uvb = uv + (size_t)batch * NFRAMES * 1024;
    const int l15 = lane & 15, l4 = lane >> 4;

    f32x4 acc[4][4];
    #pragma unroll
    for (int m = 0; m < 4; ++m)
        #pragma unroll
        for (int n = 0; n < 4; ++n)
            acc[m][n] = (f32x4)0.0f;

    for (int kt = 0; kt < 8; ++kt) {
        // ---- stage A: 128 rows x 64 k; linear LDS dest, swizzled source ----
        #pragma unroll
        for (int i = 0; i < 4; ++i) {
            int q   = i * 256 + tid;
            int row = q >> 3, d = q & 7;
            int tt  = t0 + row; if (tt > 4096) tt = 4096;   // tail clamp
            const unsigned short* src = uvb + (size_t)tt * 1024 + ih * 512
                + kt * 64 + ((d ^ (row & 7)) << 3);
            unsigned short* dst = Al + ((i * 256 + (tid & 192)) << 3);
            GLL16(src, dst);
        }
        // ---- stage B: pre-swizzled image -> purely linear copy ----
        {
            const unsigned short* srcb = Bimg2 + ((size_t)(ntile * 8 + kt)) * 8192;
            #pragma unroll
            for (int i = 0; i < 4; ++i) {
                unsigned short* dst = Bl + ((i * 256 + (tid & 192)) << 3);
                GLL16(srcb + ((i * 256 + tid) << 3), dst);
            }
        }
        __syncthreads();

        #pragma unroll
        for (int ks = 0; ks < 2; ++ks) {
            bf16x8 af[4], bfr[4];
            #pragma unroll
            for (int m = 0; m < 4; ++m) {
                int row  = wr * 64 + m * 16 + l15;
                int slot = (ks * 4 + l4) ^ (row & 7);
                af[m] = *(const bf16x8*)(Al + row * 64 + (slot << 3));
            }
            #pragma unroll
            for (int n = 0; n < 4; ++n) {
                int row  = wc * 64 + n * 16 + l15;
                int slot = (ks * 4 + l4) ^ (row & 7);
                bfr[n] = *(const bf16x8*)(Bl + row * 64 + (slot << 3));
            }
            #pragma unroll
            for (int m = 0; m < 4; ++m)
                #pragma unroll
                for (int n = 0; n < 4; ++n)
                    acc[m][n] = __builtin_amdgcn_mfma_f32_16x16x32_bf16(
                        af[m], bfr[n], acc[m][n], 0, 0, 0);
        }
        __syncthreads();
    }

    // ---- epilogue: C/D layout (m89): col = lane&15, row = (lane>>4)*4 + reg
    const int colb = nh0 + wc * 64 + l15;
    const float* g0b = g0t + (size_t)batch * NFRAMES;
    #pragma unroll
    for (int m = 0; m < 4; ++m) {
        const int trow0 = t0 + wr * 64 + m * 16 + (l4 << 2);
        #pragma unroll
        for (int r = 0; r < 4; ++r) {
            const int t = trow0 + r;
            if (t > 4096) continue;
            const float gval = (ih == 0) ? g0b[t] : 0.0f;
            const size_t rowbase = (size_t)ih * HALF_SZ
                + (size_t)batch * (NFRAMES * 512) + (size_t)t * 512;
            #pragma unroll
            for (int n = 0; n < 4; ++n)
                out[rowbase + colb + n * 16] = acc[m][n][r] + gval;
        }
    }
}

// ======================= Tier-2 (proven round-4 path) ======================
#define PADLEN   2163712
#define XP_BYTES ((size_t)NBATCH * PADLEN * 2)
#define BIMG_OFF XP_BYTES
#define BIMG_BYTES ((size_t)8 * 16 * 8192 * 2)
#define WS_NEEDED_T2 (BIMG_OFF + BIMG_BYTES)

__global__ void convert_pad(const float* __restrict__ x,
                            unsigned short* __restrict__ xp) {
    const int per = PADLEN >> 2;
    int gid = blockIdx.x * 256 + threadIdx.x;
    int b   = gid / per;
    int i4  = (gid - b * per) << 2;
    const float* xb = x + (size_t)b * NX;
    int j = i4 - 512;
    unsigned short s0, s1, s2, s3;
    if (j >= 0 && j + 3 < NX) {
        float4 f = *(const float4*)(xb + j);
        s0 = f2bf(f.x); s1 = f2bf(f.y); s2 = f2bf(f.z); s3 = f2bf(f.w);
    } else {
        unsigned short ss[4];
        #pragma unroll
        for (int e = 0; e < 4; ++e) {
            int i = i4 + e;
            float v = 0.0f;
            if (i < NX + 1024) v = xb[refl(i - 512)];
            ss[e] = f2bf(v);
        }
        s0 = ss[0]; s1 = ss[1]; s2 = ss[2]; s3 = ss[3];
    }
    union { unsigned short s[4]; uint2 u; } p;
    p.s[0] = s0; p.s[1] = s1; p.s[2] = s2; p.s[3] = s3;
    *(uint2*)(xp + (size_t)b * PADLEN + i4) = p.u;
}

__global__ void basis_to_img(const float* __restrict__ basis,
                             unsigned short* __restrict__ Bimg) {
    __shared__ float L[64][65];
    const int kt  = blockIdx.x & 15;
    const int nt  = blockIdx.x >> 4;
    const int tid = threadIdx.x;
    const int colbase = nt * 64 + (nt < 8 ? 1 : 2);
    #pragma unroll
    for (int i = 0; i < 16; ++i) {
        int r = i * 4 + (tid >> 6);
        int c = tid & 63;
        L[r][c] = basis[(size_t)(kt * 64 + r) * BASIS_LD + colbase + c];
    }
    __syncthreads();
    #pragma unroll
    for (int i = 0; i < 16; ++i) {
        int nl = i * 4 + (tid >> 6);
        int kk = tid & 63;
        int n  = nt * 64 + nl;
        int nt2 = n >> 7, row = n & 127;
        int dslot = (kk >> 3) ^ (row & 7);
        // round-4 proven layout: (nt2*16+kt) blocks of 128x64 elems
        size_t off = ((size_t)(nt2 * 16 + kt) * 128 + row) * 64 + dslot * 8 + (kk & 7);
        Bimg[off] = f2bf(L[kk][nl]);
    }
}

__global__ __launch_bounds__(256, 4) void stft_gemm2(
    const unsigned short* __restrict__ xp,
    const unsigned short* __restrict__ Bimg,
    float* __restrict__ out)
{
    __shared__ unsigned short Al[128 * 64];
    __shared__ unsigned short Bl[128 * 64];
    const int bid = blockIdx.x;
    const int wg  = (bid & 7) * (GRID / 8) + (bid >> 3);
    const int ntile = wg & 7;
    const int mtile = (wg >> 3) % MTILES;
    const int batch = wg / (MTILES * NTILES);
    const int tid  = threadIdx.x;
    const int lane = tid & 63;
    const int wr   = tid >> 7;
    const int wc   = (tid >> 6) & 1;
    const int t0   = mtile * 128;
    const int n0   = ntile * 128;
    const unsigned short* __restrict__ xpb = xp + (size_t)batch * PADLEN;
    const int l15 = lane & 15, l4 = lane >> 4;
    const unsigned short* __restrict__ bt  = Bimg + (size_t)ntile * 16 * 8192;

    f32x4 acc[4][4];
    #pragma unroll
    for (int m = 0; m < 4; ++m)
        #pragma unroll
        for (int n = 0; n < 4; ++n)
            acc[m][n] = (f32x4)0.0f;

    for (int k0 = 0; k0 < KDIM; k0 += 64) {
        #pragma unroll
        for (int i = 0; i < 4; ++i) {
            int q   = i * 256 + tid;
            int row = q >> 3, d = q & 7;
            const unsigned short* src =
                xpb + (size_t)(t0 + row) * 512 + k0 + ((d ^ (row & 7)) << 3);
            unsigned short* dst = Al + ((i * 256 + (tid & 192)) << 3);
            GLL16(src, dst);
        }
        {
            const unsigned short* srcb = bt + (size_t)(k0 >> 6) * 8192;
            #pragma unroll
            for (int i = 0; i < 4; ++i) {
                unsigned short* dst = Bl + ((i * 256 + (tid & 192)) << 3);
                GLL16(srcb + ((i * 256 + tid) << 3), dst);
            }
        }
        __syncthreads();
        #pragma unroll
        for (int ks = 0; ks < 2; ++ks) {
            const int slot0 = ks * 4 + l4;
            bf16x8 af[4], bfr[4];
            #pragma unroll
            for (int m = 0; m < 4; ++m) {
                int row = wr * 64 + m * 16 + l15;
                af[m] = *(const bf16x8*)(Al + row * 64 + ((slot0 ^ (row & 7)) << 3));
            }
            #pragma unroll
            for (int n = 0; n < 4; ++n) {
                int row = wc * 64 + n * 16 + l15;
                bfr[n] = *(const bf16x8*)(Bl + row * 64 + ((slot0 ^ (row & 7)) << 3));
            }
            #pragma unroll
            for (int m = 0; m < 4; ++m)
                #pragma unroll
                for (int n = 0; n < 4; ++n)
                    acc[m][n] = __builtin_amdgcn_mfma_f32_16x16x32_bf16(
                        af[m], bfr[n], acc[m][n], 0, 0, 0);
        }
        __syncthreads();
    }
    const int colb = n0 + wc * 64 + l15;
    #pragma unroll
    for (int m = 0; m < 4; ++m) {
        const int trow0 = t0 + wr * 64 + m * 16 + (l4 << 2);
        #pragma unroll
        for (int r = 0; r < 4; ++r) {
            const int t = trow0 + r;
            if (t > 4096) continue;
            const size_t rowbase = (size_t)batch * (NFRAMES * 512) + (size_t)t * 512;
            #pragma unroll
            for (int n = 0; n < 4; ++n) {
                const int gc = colb + n * 16;
                const size_t o = (size_t)(gc >> 9) * HALF_SZ + rowbase + (gc & 511);
                out[o] = acc[m][n][r];
            }
        }
    }
}

extern "C" void kernel_launch(void* const* d_in, const int* in_sizes, int n_in,
                              void* d_out, int out_size, void* d_ws, size_t ws_size,
                              hipStream_t stream) {
    const float* x     = (const float*)d_in[0];
    const float* basis = (const float*)d_in[1];
    float* out = (float*)d_out;

    if (ws_size >= WS_NEEDED2) {
        unsigned short* uv    = (unsigned short*)d_ws;
        unsigned short* Bimg2 = (unsigned short*)((char*)d_ws + BIMG2_OFF);
        float*          g0t   = (float*)((char*)d_ws + G0_OFF);
        g0_fill<<<(NBATCH * NFRAMES + 255) / 256, 256, 0, stream>>>(x, g0t);
        fold_pad<<<NBATCH * NFRAMES, 256, 0, stream>>>(x, uv);
        basis_to_img2<<<128, 256, 0, stream>>>(basis, Bimg2);
        stft_gemm9<<<GRID, 256, 0, stream>>>(uv, Bimg2, g0t, out);
    } else if (ws_size >= WS_NEEDED_T2) {
        // proven round-4 path (95.6 us)
        unsigned short* xp   = (unsigned short*)d_ws;
        unsigned short* Bimg = (unsigned short*)((char*)d_ws + BIMG_OFF);
        convert_pad<<<(NBATCH * (PADLEN >> 2)) / 256, 256, 0, stream>>>(x, xp);
        basis_to_img<<<256, 256, 0, stream>>>(basis, Bimg);
        stft_gemm2<<<GRID, 256, 0, stream>>>(xp, Bimg, out);
    }
}

// Round 13
// 74.415 us; speedup vs baseline: 2.0847x; 1.1857x over previous
//
#include <hip/hip_runtime.h>
#include <hip/hip_bf16.h>
#include <stdint.h>

// STFT as GEMM with DFT symmetry fold (v12 = v11 + fast fused fold):
//   unwindowed folds u[k]=f[k]+f[1024-k], v[k]=f[k]-f[1024-k] (k=1..511),
//   u[512]=f[512], v[512]=0, g0=0.08*f[0]:
//     re[t,n] = g0(t) + sum_{k=1..512} u[k]*basis[k][n+1]
//     im[t,n] =         sum_{k=1..512} v[k]*basis[k][514+n]
//   => two K=512 GEMMs (half the FLOPs), v3-proven MFMA structure (passed
//   r12 @ 88.2us total, absmax 0.5).
// v12 change: fold_pad2 = LDS-windowed fold, 4 frames/block sharing halos
//   (82 MB read vs ~268 MB effective), float4 interior loads, coalesced
//   writes, g0 fused. Everything else verbatim from the passing v11.
// Output: d_out = [re (8*4097*512) | im (8*4097*512)] fp32.

#define NX       2097152
#define NFRAMES  4097
#define NBATCH   8
#define KDIM     1024
#define BASIS_LD 1026
#define HALF_SZ  (NBATCH * NFRAMES * 512)

typedef __attribute__((ext_vector_type(8))) short bf16x8;
typedef __attribute__((ext_vector_type(4))) float f32x4;

#define GLL16(src, dst) __builtin_amdgcn_global_load_lds( \
    (const __attribute__((address_space(1))) unsigned int*)(src), \
    (__attribute__((address_space(3))) unsigned int*)(dst), 16, 0, 0)

static __device__ __forceinline__ unsigned short f2bf(float f) {
    union { float f; uint32_t u; } v; v.f = f;
    uint32_t r = (v.u + 0x7FFFu + ((v.u >> 16) & 1u)) >> 16;  // RNE
    return (unsigned short)r;
}

static __device__ __forceinline__ int refl(int i) {
    if (i < 0) return -i;
    if (i >= NX) return 2 * (NX - 1) - i;
    return i;
}

// ======================= Tier-1 (symmetry-folded) ==========================
// ws layout: uv | Bimg2 | g0t
#define UV_BYTES    ((size_t)NBATCH * NFRAMES * 1024 * 2)        // 67,125,248
#define BIMG2_OFF   UV_BYTES
#define BIMG2_BYTES ((size_t)8 * 8 * 128 * 64 * 2)               // 1 MB
#define G0_OFF      (BIMG2_OFF + BIMG2_BYTES)
#define G0_BYTES    ((size_t)NBATCH * NFRAMES * 4)
#define WS_NEEDED2  (G0_OFF + G0_BYTES)

#define MTILES 33
#define NTILES 8
#define GRID   (NBATCH * MTILES * NTILES)  // 2112 = 8 * 264

#define NGROUPS 1025   // ceil(4097/4) frame-groups per batch

// Kernel: fused fold + g0. One block = 4 consecutive frames of one batch.
// LDS holds the union of their windows: 2560 floats (halos shared).
//   uv[(b*4097+t)*1024 + (k-1)]       = u[k]   k=1..512
//   uv[(b*4097+t)*1024 + 512 + (k-1)] = v[k]
__global__ __launch_bounds__(256) void fold_pad2(
    const float* __restrict__ x,
    unsigned short* __restrict__ uv,
    float* __restrict__ g0t)
{
    __shared__ float w[2560];                // 10 KB
    const int blk = blockIdx.x;              // 0 .. 8*1025-1
    const int b = blk / NGROUPS, g = blk - b * NGROUPS;
    const int tid = threadIdx.x;
    const float* xb = x + (size_t)b * NX;
    const int base = g * 2048 - 512;         // first x index of group window

    if (g >= 1 && g <= 1023) {
        // interior: aligned float4, fully in-bounds
        // (g=1: base=1536; g=1023: base+2559 = 2097151 = NX-1)
        #pragma unroll
        for (int i = 0; i < 3; ++i) {
            int i4 = tid + i * 256;
            if (i4 < 640)
                *(float4*)&w[i4 * 4] = *(const float4*)(xb + base + i4 * 4);
        }
    } else {
        // edge groups (g=0 left reflect, g=1024 right reflect)
        #pragma unroll
        for (int i = 0; i < 3; ++i) {
            int i4 = tid + i * 256;
            if (i4 < 640) {
                #pragma unroll
                for (int e = 0; e < 4; ++e)
                    w[i4 * 4 + e] = xb[refl(base + i4 * 4 + e)];
            }
        }
    }
    __syncthreads();

    const int k1 = 2 * tid + 1, k2 = k1 + 1;    // 1..511 / 2..512
    for (int f = 0; f < 4; ++f) {
        const int t = g * 4 + f;
        if (t > 4096) break;
        const float* wf = w + f * 512;          // frame window = wf[0..1023]
        float a1 = wf[k1],  b1v = wf[1024 - k1];
        float a2 = wf[k2],  b2v = wf[1024 - k2];
        float u1 = a1 + b1v, v1 = a1 - b1v;
        float u2 = (k2 == 512) ? a2 : (a2 + b2v);   // k=512 appears once
        float v2 = a2 - b2v;                         // = 0 at k2==512
        union { unsigned short s[2]; uint32_t u; } pu, pv;
        pu.s[0] = f2bf(u1); pu.s[1] = f2bf(u2);
        pv.s[0] = f2bf(v1); pv.s[1] = f2bf(v2);
        unsigned short* row = uv + ((size_t)b * NFRAMES + t) * 1024;
        *(uint32_t*)(row + 2 * tid)       = pu.u;
        *(uint32_t*)(row + 512 + 2 * tid) = pv.u;
        if (tid == 0) g0t[b * NFRAMES + t] = 0.08f * wf[0];
    }
}

// Kernel: basis rows 1..512 -> Bimg2 [nt2(8)][kt(8)][row(128)][slot(8)][8],
// slot = (klocal>>3) ^ (row&7): pre-swizzled for linear global_load_lds.
// Stores the TRUE basis (incl. window) — fold is unwindowed.
__global__ void basis_to_img2(const float* __restrict__ basis,
                              unsigned short* __restrict__ Bimg2) {
    __shared__ float L[64][65];
    const int kt   = blockIdx.x & 7;      // 64-wide k tile (k = 1+kt*64+r)
    const int nt64 = blockIdx.x >> 3;     // 64-wide n tile (0..15)
    const int tid  = threadIdx.x;
    const int colbase = nt64 * 64 + (nt64 < 8 ? 1 : 2);  // re: +1, im: +2
    #pragma unroll
    for (int i = 0; i < 16; ++i) {
        int r = i * 4 + (tid >> 6);       // k-local
        int c = tid & 63;
        L[r][c] = basis[(size_t)(kt * 64 + r + 1) * BASIS_LD + colbase + c];
    }
    __syncthreads();
    #pragma unroll
    for (int i = 0; i < 16; ++i) {
        int nl  = i * 4 + (tid >> 6);
        int kkl = tid & 63;
        int gn  = nt64 * 64 + nl;         // 0..1023 (re 0..511 | im 512..1023)
        int nt2 = gn >> 7, row = gn & 127;
        int dslot = (kkl >> 3) ^ (row & 7);
        size_t off = ((size_t)(nt2 * 8 + kt) * 128 + row) * 64 + dslot * 8 + (kkl & 7);
        Bimg2[off] = f2bf(L[kkl][nl]);
    }
}

// Kernel: K=512 GEMM, v3 structure verbatim (single-buffered, GLL16 + XOR
// chunk swizzle, 2 barriers/K-tile, 4 blocks/CU). ntile<4: re (u half),
// ntile>=4: im (v half). g0 added in epilogue for re.
__global__ __launch_bounds__(256, 4) void stft_gemm9(
    const unsigned short* __restrict__ uv,
    const unsigned short* __restrict__ Bimg2,
    const float* __restrict__ g0t,
    float* __restrict__ out)
{
    __shared__ unsigned short Al[128 * 64];  // 16 KB
    __shared__ unsigned short Bl[128 * 64];  // 16 KB

    const int bid = blockIdx.x;
    const int wg  = (bid & 7) * (GRID / 8) + (bid >> 3);   // bijective XCD swizzle
    const int ntile = wg & 7;
    const int mtile = (wg >> 3) % MTILES;
    const int batch = wg / (MTILES * NTILES);

    const int tid  = threadIdx.x;
    const int lane = tid & 63;
    const int wr   = tid >> 7;
    const int wc   = (tid >> 6) & 1;
    const int t0   = mtile * 128;
    const int ih   = (ntile >= 4);            // 0=re(u), 1=im(v)
    const int nh0  = (ntile & 3) * 128;       // col origin within half

    const unsigned short* __restrict__ uvb = uv + (size_t)batch * NFRAMES * 1024;
    const int l15 = lane & 15, l4 = lane >> 4;

    f32x4 acc[4][4];
    #pragma unroll
    for (int m = 0; m < 4; ++m)
        #pragma unroll
        for (int n = 0; n < 4; ++n)
            acc[m][n] = (f32x4)0.0f;

    for (int kt = 0; kt < 8; ++kt) {
        // ---- stage A: 128 rows x 64 k; linear LDS dest, swizzled source ----
        #pragma unroll
        for (int i = 0; i < 4; ++i) {
            int q   = i * 256 + tid;
            int row = q >> 3, d = q & 7;
            int tt  = t0 + row; if (tt > 4096) tt = 4096;   // tail clamp
            const unsigned short* src = uvb + (size_t)tt * 1024 + ih * 512
                + kt * 64 + ((d ^ (row & 7)) << 3);
            unsigned short* dst = Al + ((i * 256 + (tid & 192)) << 3);
            GLL16(src, dst);
        }
        // ---- stage B: pre-swizzled image -> purely linear copy ----
        {
            const unsigned short* srcb = Bimg2 + ((size_t)(ntile * 8 + kt)) * 8192;
            #pragma unroll
            for (int i = 0; i < 4; ++i) {
                unsigned short* dst = Bl + ((i * 256 + (tid & 192)) << 3);
                GLL16(srcb + ((i * 256 + tid) << 3), dst);
            }
        }
        __syncthreads();

        #pragma unroll
        for (int ks = 0; ks < 2; ++ks) {
            bf16x8 af[4], bfr[4];
            #pragma unroll
            for (int m = 0; m < 4; ++m) {
                int row  = wr * 64 + m * 16 + l15;
                int slot = (ks * 4 + l4) ^ (row & 7);
                af[m] = *(const bf16x8*)(Al + row * 64 + (slot << 3));
            }
            #pragma unroll
            for (int n = 0; n < 4; ++n) {
                int row  = wc * 64 + n * 16 + l15;
                int slot = (ks * 4 + l4) ^ (row & 7);
                bfr[n] = *(const bf16x8*)(Bl + row * 64 + (slot << 3));
            }
            #pragma unroll
            for (int m = 0; m < 4; ++m)
                #pragma unroll
                for (int n = 0; n < 4; ++n)
                    acc[m][n] = __builtin_amdgcn_mfma_f32_16x16x32_bf16(
                        af[m], bfr[n], acc[m][n], 0, 0, 0);
        }
        __syncthreads();
    }

    // ---- epilogue: C/D layout (m89): col = lane&15, row = (lane>>4)*4 + reg
    const int colb = nh0 + wc * 64 + l15;
    const float* g0b = g0t + (size_t)batch * NFRAMES;
    #pragma unroll
    for (int m = 0; m < 4; ++m) {
        const int trow0 = t0 + wr * 64 + m * 16 + (l4 << 2);
        #pragma unroll
        for (int r = 0; r < 4; ++r) {
            const int t = trow0 + r;
            if (t > 4096) continue;
            const float gval = (ih == 0) ? g0b[t] : 0.0f;
            const size_t rowbase = (size_t)ih * HALF_SZ
                + (size_t)batch * (NFRAMES * 512) + (size_t)t * 512;
            #pragma unroll
            for (int n = 0; n < 4; ++n)
                out[rowbase + colb + n * 16] = acc[m][n][r] + gval;
        }
    }
}

// ======================= Tier-2 (proven round-4 path) ======================
#define PADLEN   2163712
#define XP_BYTES ((size_t)NBATCH * PADLEN * 2)
#define BIMG_OFF XP_BYTES
#define BIMG_BYTES ((size_t)8 * 16 * 8192 * 2)
#define WS_NEEDED_T2 (BIMG_OFF + BIMG_BYTES)

__global__ void convert_pad(const float* __restrict__ x,
                            unsigned short* __restrict__ xp) {
    const int per = PADLEN >> 2;
    int gid = blockIdx.x * 256 + threadIdx.x;
    int b   = gid / per;
    int i4  = (gid - b * per) << 2;
    const float* xb = x + (size_t)b * NX;
    int j = i4 - 512;
    unsigned short s0, s1, s2, s3;
    if (j >= 0 && j + 3 < NX) {
        float4 f = *(const float4*)(xb + j);
        s0 = f2bf(f.x); s1 = f2bf(f.y); s2 = f2bf(f.z); s3 = f2bf(f.w);
    } else {
        unsigned short ss[4];
        #pragma unroll
        for (int e = 0; e < 4; ++e) {
            int i = i4 + e;
            float v = 0.0f;
            if (i < NX + 1024) v = xb[refl(i - 512)];
            ss[e] = f2bf(v);
        }
        s0 = ss[0]; s1 = ss[1]; s2 = ss[2]; s3 = ss[3];
    }
    union { unsigned short s[4]; uint2 u; } p;
    p.s[0] = s0; p.s[1] = s1; p.s[2] = s2; p.s[3] = s3;
    *(uint2*)(xp + (size_t)b * PADLEN + i4) = p.u;
}

__global__ void basis_to_img(const float* __restrict__ basis,
                             unsigned short* __restrict__ Bimg) {
    __shared__ float L[64][65];
    const int kt  = blockIdx.x & 15;
    const int nt  = blockIdx.x >> 4;
    const int tid = threadIdx.x;
    const int colbase = nt * 64 + (nt < 8 ? 1 : 2);
    #pragma unroll
    for (int i = 0; i < 16; ++i) {
        int r = i * 4 + (tid >> 6);
        int c = tid & 63;
        L[r][c] = basis[(size_t)(kt * 64 + r) * BASIS_LD + colbase + c];
    }
    __syncthreads();
    #pragma unroll
    for (int i = 0; i < 16; ++i) {
        int nl = i * 4 + (tid >> 6);
        int kk = tid & 63;
        int n  = nt * 64 + nl;
        int nt2 = n >> 7, row = n & 127;
        int dslot = (kk >> 3) ^ (row & 7);
        size_t off = ((size_t)(nt2 * 16 + kt) * 128 + row) * 64 + dslot * 8 + (kk & 7);
        Bimg[off] = f2bf(L[kk][nl]);
    }
}

__global__ __launch_bounds__(256, 4) void stft_gemm2(
    const unsigned short* __restrict__ xp,
    const unsigned short* __restrict__ Bimg,
    float* __restrict__ out)
{
    __shared__ unsigned short Al[128 * 64];
    __shared__ unsigned short Bl[128 * 64];
    const int bid = blockIdx.x;
    const int wg  = (bid & 7) * (GRID / 8) + (bid >> 3);
    const int ntile = wg & 7;
    const int mtile = (wg >> 3) % MTILES;
    const int batch = wg / (MTILES * NTILES);
    const int tid  = threadIdx.x;
    const int lane = tid & 63;
    const int wr   = tid >> 7;
    const int wc   = (tid >> 6) & 1;
    const int t0   = mtile * 128;
    const int n0   = ntile * 128;
    const unsigned short* __restrict__ xpb = xp + (size_t)batch * PADLEN;
    const int l15 = lane & 15, l4 = lane >> 4;
    const unsigned short* __restrict__ bt  = Bimg + (size_t)ntile * 16 * 8192;

    f32x4 acc[4][4];
    #pragma unroll
    for (int m = 0; m < 4; ++m)
        #pragma unroll
        for (int n = 0; n < 4; ++n)
            acc[m][n] = (f32x4)0.0f;

    for (int k0 = 0; k0 < KDIM; k0 += 64) {
        #pragma unroll
        for (int i = 0; i < 4; ++i) {
            int q   = i * 256 + tid;
            int row = q >> 3, d = q & 7;
            const unsigned short* src =
                xpb + (size_t)(t0 + row) * 512 + k0 + ((d ^ (row & 7)) << 3);
            unsigned short* dst = Al + ((i * 256 + (tid & 192)) << 3);
            GLL16(src, dst);
        }
        {
            const unsigned short* srcb = bt + (size_t)(k0 >> 6) * 8192;
            #pragma unroll
            for (int i = 0; i < 4; ++i) {
                unsigned short* dst = Bl + ((i * 256 + (tid & 192)) << 3);
                GLL16(srcb + ((i * 256 + tid) << 3), dst);
            }
        }
        __syncthreads();
        #pragma unroll
        for (int ks = 0; ks < 2; ++ks) {
            const int slot0 = ks * 4 + l4;
            bf16x8 af[4], bfr[4];
            #pragma unroll
            for (int m = 0; m < 4; ++m) {
                int row = wr * 64 + m * 16 + l15;
                af[m] = *(const bf16x8*)(Al + row * 64 + ((slot0 ^ (row & 7)) << 3));
            }
            #pragma unroll
            for (int n = 0; n < 4; ++n) {
                int row = wc * 64 + n * 16 + l15;
                bfr[n] = *(const bf16x8*)(Bl + row * 64 + ((slot0 ^ (row & 7)) << 3));
            }
            #pragma unroll
            for (int m = 0; m < 4; ++m)
                #pragma unroll
                for (int n = 0; n < 4; ++n)
                    acc[m][n] = __builtin_amdgcn_mfma_f32_16x16x32_bf16(
                        af[m], bfr[n], acc[m][n], 0, 0, 0);
        }
        __syncthreads();
    }
    const int colb = n0 + wc * 64 + l15;
    #pragma unroll
    for (int m = 0; m < 4; ++m) {
        const int trow0 = t0 + wr * 64 + m * 16 + (l4 << 2);
        #pragma unroll
        for (int r = 0; r < 4; ++r) {
            const int t = trow0 + r;
            if (t > 4096) continue;
            const size_t rowbase = (size_t)batch * (NFRAMES * 512) + (size_t)t * 512;
            #pragma unroll
            for (int n = 0; n < 4; ++n) {
                const int gc = colb + n * 16;
                const size_t o = (size_t)(gc >> 9) * HALF_SZ + rowbase + (gc & 511);
                out[o] = acc[m][n][r];
            }
        }
    }
}

extern "C" void kernel_launch(void* const* d_in, const int* in_sizes, int n_in,
                              void* d_out, int out_size, void* d_ws, size_t ws_size,
                              hipStream_t stream) {
    const float* x     = (const float*)d_in[0];
    const float* basis = (const float*)d_in[1];
    float* out = (float*)d_out;

    if (ws_size >= WS_NEEDED2) {
        unsigned short* uv    = (unsigned short*)d_ws;
        unsigned short* Bimg2 = (unsigned short*)((char*)d_ws + BIMG2_OFF);
        float*          g0t   = (float*)((char*)d_ws + G0_OFF);
        fold_pad2<<<NBATCH * NGROUPS, 256, 0, stream>>>(x, uv, g0t);
        basis_to_img2<<<128, 256, 0, stream>>>(basis, Bimg2);
        stft_gemm9<<<GRID, 256, 0, stream>>>(uv, Bimg2, g0t, out);
    } else if (ws_size >= WS_NEEDED_T2) {
        // proven round-4 path (95.6 us)
        unsigned short* xp   = (unsigned short*)d_ws;
        unsigned short* Bimg = (unsigned short*)((char*)d_ws + BIMG_OFF);
        convert_pad<<<(NBATCH * (PADLEN >> 2)) / 256, 256, 0, stream>>>(x, xp);
        basis_to_img<<<256, 256, 0, stream>>>(basis, Bimg);
        stft_gemm2<<<GRID, 256, 0, stream>>>(xp, Bimg, out);
    }
}